// Round 11
// baseline (171.405 us; speedup 1.0000x reference)
//
#include <hip/hip_runtime.h>
#include <math.h>

#define N_Q 20000
#define KK 48
#define CC 64
#define FFD 256

// ws float offsets
#define TW_WOB   0        // 2048 u32: out_w B-frags [ks2][nb4][lane64][4] (ffn att GEMM)
#define TW_WVT   4096     // 2048 u32: Wv B-frags [ks2][nb4][lane64][4]   (attn V-GEMM)
#define TW_L1B   8192     // 8192 u32: lin1 B-frags  [ks2][nb16][lane64][4]
#define TW_L2B   16384    // 8192 u32: lin2 B-frags  [ks8][nb4][lane64][4]
#define TW_OLB   24576    // 2048 u32: outl B-frags  [ks2][nb4][lane64][4]
#define ST_OFF   32768    // 256 f32: sum1,sumsq1,sum2,sumsq2
#define M_OFF    33024    // bf16 M_all[n][h*64+c], 20000*256 ushorts
#define VF_OFF   2593024  // bf16 vfeat table, 80000*64 ushorts (10.24 MB)
#define CTX_OFF  5153024  // bf16 ctx[n][c], 20000*64 ushorts (2.56 MB)

typedef short bf16x8 __attribute__((ext_vector_type(8)));
typedef float f32x4  __attribute__((ext_vector_type(4)));
typedef float f32x2  __attribute__((ext_vector_type(2)));

// v_cvt_pk_bf16_f32: 1 VALU op, RNE.
__device__ __forceinline__ unsigned pk2(float a, float b) {
    unsigned r;
    asm("v_cvt_pk_bf16_f32 %0, %1, %2" : "=v"(r) : "v"(a), "v"(b));
    return r;
}
__device__ __forceinline__ unsigned f2bf(float a) {
    unsigned r;
    asm("v_cvt_pk_bf16_f32 %0, %1, 0" : "=v"(r) : "v"(a));
    return r & 0xffffu;
}
// v_pk_fma_f32 (VOP3P packed f32, CDNA2+): 2 IEEE FMAs in 1 instruction.
__device__ __forceinline__ f32x2 pkfma(f32x2 s0, f32x2 s1, f32x2 s2) {
    f32x2 d;
    asm("v_pk_fma_f32 %0, %1, %2, %3" : "=v"(d) : "v"(s0), "v"(s1), "v"(s2));
    return d;
}
__device__ __forceinline__ float bflo(unsigned u) { return __uint_as_float(u << 16); }
__device__ __forceinline__ float bfhi(unsigned u) { return __uint_as_float(u & 0xffff0000u); }
__device__ __forceinline__ bf16x8 ldfrag(const unsigned short* p) {
    return *(const bf16x8*)p;
}
union U84 { unsigned u[4]; bf16x8 v; };

// ---------------------------------------------------------------------------
// prep_m: fused. Blocks 0..249: m-work (self-packed QB/KB frags from in_w —
// bit-identical pk2). Blocks 250..5369: prep-work (vfeat bf16 table, weight
// B-frag packs, stats zero). Single launch removes the prep->m dependency.
// ---------------------------------------------------------------------------
__global__ __launch_bounds__(256) void prep_m(
    const float* __restrict__ in_w, const float* __restrict__ out_w,
    const float* __restrict__ lin1_w, const float* __restrict__ lin2_w,
    const float* __restrict__ outl_w, const float* __restrict__ vfeat,
    const float* __restrict__ qcoord, const float* __restrict__ q_w,
    const float* __restrict__ q_b, const float* __restrict__ in_b,
    float* __restrict__ tw, unsigned short* __restrict__ vfeat_bf,
    float* __restrict__ stats, unsigned short* __restrict__ M_all)
{
    __shared__ __align__(16) unsigned short sQF[80*72];
    __shared__ __align__(16) unsigned short sQ[80*72];

    if (blockIdx.x >= 250) {
        // ---------------- prep path ----------------
        int t = (blockIdx.x - 250) * 256 + threadIdx.x;
        unsigned* twu = (unsigned*)tw;
        if (t < 1280000) {                          // vfeat -> bf16 (4 elems/thread)
            float4 v = ((const float4*)vfeat)[t];
            uint2 p; p.x = pk2(v.x, v.y); p.y = pk2(v.z, v.w);
            ((uint2*)vfeat_bf)[t] = p;
        }
        if (t < 256) stats[t] = 0.0f;
        if (t < 4096) {
            if (t < 2048) {                        // WOB: att = ctx @ out_w^T (ffn)
                int p = t;
                int j2 = p & 3, lane = (p >> 2) & 63, nb = (p >> 8) & 3, ks = p >> 10;
                int nn = nb*16 + (lane & 15), k = ks*32 + (lane >> 4)*8 + 2*j2;
                twu[TW_WOB + p] = pk2(out_w[nn*64 + k], out_w[nn*64 + k + 1]);
            }
        } else if (t < 8192) {
            if (t < 6144) {                        // VB: Wv B-frags (attn V-GEMM)
                int p = t - 4096;
                int j2 = p & 3, lane = (p >> 2) & 63, nb = (p >> 8) & 3, ks = p >> 10;
                int nn = nb*16 + (lane & 15), k = ks*32 + (lane >> 4)*8 + 2*j2;
                twu[TW_WVT + p] = pk2(in_w[(128 + nn)*64 + k], in_w[(128 + nn)*64 + k + 1]);
            }
        } else if (t < 16384) {                    // L1B: H = att @ lin1_w^T
            int p = t - 8192;
            int j2 = p & 3, lane = (p >> 2) & 63, nb = (p >> 8) & 15, ks = p >> 12;
            int n = nb*16 + (lane & 15), k = ks*32 + (lane >> 4)*8 + 2*j2;
            twu[TW_L1B + p] = pk2(lin1_w[n*64 + k], lin1_w[n*64 + k + 1]);
        } else if (t < 24576) {                    // L2B: Y = H @ lin2_w^T
            int p = t - 16384;
            int j2 = p & 3, lane = (p >> 2) & 63, nb = (p >> 8) & 3, ks = p >> 10;
            int n = nb*16 + (lane & 15), k = ks*32 + (lane >> 4)*8 + 2*j2;
            twu[TW_L2B + p] = pk2(lin2_w[n*256 + k], lin2_w[n*256 + k + 1]);
        } else if (t < 26624) {                    // OLB: z = xn @ outl_w^T
            int p = t - 24576;
            int j2 = p & 3, lane = (p >> 2) & 63, nb = (p >> 8) & 3, ks = p >> 10;
            int n = nb*16 + (lane & 15), k = ks*32 + (lane >> 4)*8 + 2*j2;
            twu[TW_OLB + p] = pk2(outl_w[n*64 + k], outl_w[n*64 + k + 1]);
        }
        return;
    }

    // ---------------- m path (blocks 0..249) ----------------
    int t = threadIdx.x, base = blockIdx.x * 80;
    int colq = (t*4) & 63;
    float qwv[12];
    #pragma unroll
    for (int j = 0; j < 12; ++j) qwv[j] = q_w[colq*3 + j];
    float4 qb4 = *(const float4*)&q_b[colq];
    #pragma unroll
    for (int i = 0; i < 5; ++i) {
        int e = i*1024 + t*4, r = e >> 6, n = base + r;
        float c0 = qcoord[n*3], c1 = qcoord[n*3+1], c2 = qcoord[n*3+2];
        float f0 = fmaxf(fmaf(qwv[2],  c2, fmaf(qwv[1],  c1, fmaf(qwv[0], c0, qb4.x))), 0.f);
        float f1 = fmaxf(fmaf(qwv[5],  c2, fmaf(qwv[4],  c1, fmaf(qwv[3], c0, qb4.y))), 0.f);
        float f2 = fmaxf(fmaf(qwv[8],  c2, fmaf(qwv[7],  c1, fmaf(qwv[6], c0, qb4.z))), 0.f);
        float f3 = fmaxf(fmaf(qwv[11], c2, fmaf(qwv[10], c1, fmaf(qwv[9], c0, qb4.w))), 0.f);
        uint2 p; p.x = pk2(f0, f1); p.y = pk2(f2, f3);
        *(uint2*)&sQF[r*72 + colq] = p;
    }
    int w = t >> 6, lane = t & 63, l16 = lane & 15, quad = lane >> 4;
    // self-pack qbf (Wq B-frags): contiguous 8 f32 of in_w row (w*16+l16)
    bf16x8 qbf[2], kbf[4];
    {
        const float* qrow = in_w + (w*16 + l16)*64;
        #pragma unroll
        for (int ks = 0; ks < 2; ++ks) {
            float4 aa = *(const float4*)&qrow[ks*32 + quad*8];
            float4 bb = *(const float4*)&qrow[ks*32 + quad*8 + 4];
            U84 u;
            u.u[0] = pk2(aa.x, aa.y); u.u[1] = pk2(aa.z, aa.w);
            u.u[2] = pk2(bb.x, bb.y); u.u[3] = pk2(bb.z, bb.w);
            qbf[ks] = u.v;
        }
        // self-pack kbf (Wk B-frags, head w, K=16 zero-pad for quad>=2)
        #pragma unroll
        for (int nb = 0; nb < 4; ++nb) {
            U84 u;
            if (quad < 2) {
                int jj = nb*16 + l16;
                #pragma unroll
                for (int j2 = 0; j2 < 4; ++j2) {
                    int k = quad*8 + 2*j2;
                    u.u[j2] = pk2(in_w[(64 + w*16 + k)*64 + jj],
                                  in_w[(64 + w*16 + k + 1)*64 + jj]);
                }
            } else {
                u.u[0] = u.u[1] = u.u[2] = u.u[3] = 0;
            }
            kbf[nb] = u.v;
        }
    }
    __syncthreads();

    int cq = w*16 + l16;
    float bq = in_b[cq];
    #pragma unroll
    for (int mb = 0; mb < 5; ++mb) {
        bf16x8 a0 = ldfrag(&sQF[(mb*16 + l16)*72 + quad*8]);
        bf16x8 a1 = ldfrag(&sQF[(mb*16 + l16)*72 + 32 + quad*8]);
        f32x4 acc = {0.f, 0.f, 0.f, 0.f};
        acc = __builtin_amdgcn_mfma_f32_16x16x32_bf16(a0, qbf[0], acc, 0, 0, 0);
        acc = __builtin_amdgcn_mfma_f32_16x16x32_bf16(a1, qbf[1], acc, 0, 0, 0);
        #pragma unroll
        for (int reg = 0; reg < 4; ++reg) {
            int row = mb*16 + quad*4 + reg;
            sQ[row*72 + cq] = (unsigned short)f2bf((acc[reg] + bq) * 0.25f);
        }
    }
    // per-head M GEMM: head h = w reads exactly the cols it wrote (in-order)
    #pragma unroll
    for (int mb = 0; mb < 5; ++mb) {
        bf16x8 a = {0,0,0,0,0,0,0,0};
        if (quad < 2) a = ldfrag(&sQ[(mb*16 + l16)*72 + w*16 + quad*8]);
        f32x4 acc[4];
        #pragma unroll
        for (int nb = 0; nb < 4; ++nb) {
            f32x4 z = {0.f, 0.f, 0.f, 0.f};
            acc[nb] = __builtin_amdgcn_mfma_f32_16x16x32_bf16(a, kbf[nb], z, 0, 0, 0);
        }
        #pragma unroll
        for (int nb = 0; nb < 4; ++nb)
            #pragma unroll
            for (int reg = 0; reg < 4; ++reg) {
                int r = base + mb*16 + quad*4 + reg, j = nb*16 + l16;
                M_all[(size_t)r*256 + w*64 + j] = (unsigned short)f2bf(acc[nb][reg]);
            }
    }
}

// ---------------------------------------------------------------------------
// attn: 4 queries/block (256 thr, 4 independent waves, disjoint LDS quarters,
// barrier-free). 16B bf16 gathers -> bf16 KF in LDS [key][c^swz]: tight
// 64-col pitch + T2 XOR swizzle, 0 bank conflicts (R7-verified).
// Posenc via v_pk_fma_f32 (paired channels, mirrored eval order ->
// bit-identical to scalar fmaf nest). launch_bounds(256,4): no VGPR clamp
// (R7 lesson). R9 A/B: keep 4q blocks.
// ---------------------------------------------------------------------------
__global__ __launch_bounds__(256, 4) void attn_kernel(
    const unsigned short* __restrict__ vfeat_bf, const float* __restrict__ vcoord,
    const float* __restrict__ qcoord, const int* __restrict__ kidx,
    const float* __restrict__ kpos_w, const float* __restrict__ kpos_b,
    const float* __restrict__ in_b,
    const float* __restrict__ tw, const unsigned short* __restrict__ M_all,
    unsigned short* __restrict__ ctx_bf)
{
    __shared__ __align__(16) unsigned short skf2[4][KK*64];  // 4 x 6144 B
    int wv = threadIdx.x >> 6, c = threadIdx.x & 63;
    int n = blockIdx.x * 4 + wv;
    unsigned short* skf = skf2[wv];
    int l16 = c & 15, quad = c >> 4;

    // ---- early loads: M score B-frags (dup head l16&3) + Wv B-frags ----
    const unsigned short* Mrow = M_all + (size_t)n*256 + (l16 & 3)*64 + quad*8;
    bf16x8 mf0 = ldfrag(Mrow);          // k-dim c = quad*8 + j      (ks=0)
    bf16x8 mf1 = ldfrag(Mrow + 32);     // k-dim c = 32 + quad*8 + j (ks=1)
    const unsigned* VBu = (const unsigned*)(tw + TW_WVT);
    bf16x8 wvf[2][4];
    #pragma unroll
    for (int ks = 0; ks < 2; ++ks)
        #pragma unroll
        for (int nb = 0; nb < 4; ++nb)
            wvf[ks][nb] = ldfrag((const unsigned short*)&VBu[((ks*4 + nb)*64 + c)*4]);

    float qc0 = qcoord[n*3+0], qc1 = qcoord[n*3+1], qc2 = qcoord[n*3+2];

    // lanes 0..47: key index + relative coords
    int kread = c < 48 ? c : 47;
    int idxv = kidx[(size_t)n*KK + kread];
    int sfe = idxv < 0 ? 0 : idxv;
    float rl0 = vcoord[sfe*3+0] - qc0;
    float rl1 = vcoord[sfe*3+1] - qc1;
    float rl2 = vcoord[sfe*3+2] - qc2;

    // kpos params for this lane's 8 channels (j = (c&7)*8 + 0..7),
    // re-paired for v_pk_fma_f32: wp[q2][j] = {w[k0][j], w[k1][j]}.
    int o8 = c >> 3, jb8 = (c & 7) * 8;
    float w8[24], b8[8];
    #pragma unroll
    for (int q = 0; q < 6; ++q)
        *(float4*)&w8[q*4] = *(const float4*)(kpos_w + jb8*3 + q*4);
    *(float4*)&b8[0] = *(const float4*)(kpos_b + jb8);
    *(float4*)&b8[4] = *(const float4*)(kpos_b + jb8 + 4);
    f32x2 wp[4][3], bp2[4];
    #pragma unroll
    for (int q2 = 0; q2 < 4; ++q2) {
        int k0 = 2*q2, k1 = 2*q2 + 1;
        wp[q2][0] = f32x2{w8[3*k0+0], w8[3*k1+0]};
        wp[q2][1] = f32x2{w8[3*k0+1], w8[3*k1+1]};
        wp[q2][2] = f32x2{w8[3*k0+2], w8[3*k1+2]};
        bp2[q2]   = f32x2{b8[k0], b8[k1]};
    }

    // ---- issue all 6 gather loads (16B/lane: 8 bf16 channels) ----
    uint4 fv[6];
    #pragma unroll
    for (int i = 0; i < 6; ++i) {
        int row = 8*i + o8;
        int si = __shfl(idxv, row);
        si = si < 0 ? 0 : si;
        fv[i] = *(const uint4*)(vfeat_bf + (size_t)si*64 + jb8);
    }
    // ---- consume: unpack, add packed-f32 posenc, repack to swizzled LDS ----
    #pragma unroll
    for (int i = 0; i < 6; ++i) {
        int row = 8*i + o8;
        float rr0 = __shfl(rl0, row), rr1 = __shfl(rl1, row), rr2 = __shfl(rl2, row);
        f32x2 rp0 = {rr0, rr0}, rp1 = {rr1, rr1}, rp2 = {rr2, rr2};
        unsigned uu[4] = {fv[i].x, fv[i].y, fv[i].z, fv[i].w};
        unsigned pp[4];
        #pragma unroll
        for (int q2 = 0; q2 < 4; ++q2) {
            // mirrored order: b + w2*rr2 -> +w1*rr1 -> +w0*rr0 (bit-identical
            // to the old scalar fmaf nest, per element).
            f32x2 acc = pkfma(wp[q2][2], rp2, bp2[q2]);
            acc = pkfma(wp[q2][1], rp1, acc);
            acc = pkfma(wp[q2][0], rp0, acc);
            float gl = bflo(uu[q2]) + fmaxf(acc.x, 0.0f);
            float gh = bfhi(uu[q2]) + fmaxf(acc.y, 0.0f);
            pp[q2] = pk2(gl, gh);
        }
        uint4 st; st.x = pp[0]; st.y = pp[1]; st.z = pp[2]; st.w = pp[3];
        *(uint4*)&skf[row*64 + (jb8 ^ ((row & 7) << 3))] = st;
    }

    // ---- scores: S = KF @ M via MFMA; D[row=key-in-tile, col=head] ----
    unsigned long long vm = __ballot(c < 48 && idxv >= 0);
    bf16x8 a0s[3], a1s[3];
    float S[3][4];
    #pragma unroll
    for (int mb = 0; mb < 3; ++mb) {
        int r0 = mb*16 + l16, sw = (l16 & 7) << 3;
        a0s[mb] = ldfrag(&skf[r0*64 + ((quad*8) ^ sw)]);
        a1s[mb] = ldfrag(&skf[r0*64 + ((32 + quad*8) ^ sw)]);
        f32x4 acc = {0.f, 0.f, 0.f, 0.f};
        acc = __builtin_amdgcn_mfma_f32_16x16x32_bf16(a0s[mb], mf0, acc, 0, 0, 0);
        acc = __builtin_amdgcn_mfma_f32_16x16x32_bf16(a1s[mb], mf1, acc, 0, 0, 0);
        #pragma unroll
        for (int r = 0; r < 4; ++r) {
            int kk = mb*16 + quad*4 + r;
            S[mb][r] = ((vm >> kk) & 1ull) ? acc[r] : -1e30f;
        }
    }

    // ---- softmax over the 48 keys of head (l16&3); reduce across quads ----
    float mx = S[0][0];
    #pragma unroll
    for (int mb = 0; mb < 3; ++mb)
        #pragma unroll
        for (int r = 0; r < 4; ++r) mx = fmaxf(mx, S[mb][r]);
    mx = fmaxf(mx, __shfl_xor(mx, 16));
    mx = fmaxf(mx, __shfl_xor(mx, 32));
    float p[3][4], es = 0.f;
    #pragma unroll
    for (int mb = 0; mb < 3; ++mb)
        #pragma unroll
        for (int r = 0; r < 4; ++r) { p[mb][r] = __expf(S[mb][r] - mx); es += p[mb][r]; }
    es += __shfl_xor(es, 16);
    es += __shfl_xor(es, 32);
    float rinv = 1.0f / es;
    #pragma unroll
    for (int mb = 0; mb < 3; ++mb)
        #pragma unroll
        for (int r = 0; r < 4; ++r) p[mb][r] *= rinv;

    // ---- V = KF @ Wv^T (MFMA, reuses a-frags); ctx = P @ V (f32) ----
    float cacc0 = 0.f, cacc1 = 0.f, cacc2 = 0.f, cacc3 = 0.f;
    #pragma unroll
    for (int mb = 0; mb < 3; ++mb) {
        f32x4 av[4];
        #pragma unroll
        for (int nb = 0; nb < 4; ++nb) {
            f32x4 z = {0.f, 0.f, 0.f, 0.f};
            z = __builtin_amdgcn_mfma_f32_16x16x32_bf16(a0s[mb], wvf[0][nb], z, 0, 0, 0);
            av[nb] = __builtin_amdgcn_mfma_f32_16x16x32_bf16(a1s[mb], wvf[1][nb], z, 0, 0, 0);
        }
        #pragma unroll
        for (int r = 0; r < 4; ++r) {
            float pv = p[mb][r];
            float p0 = __shfl(pv, quad*16 + 0);
            float p1 = __shfl(pv, quad*16 + 1);
            float p2 = __shfl(pv, quad*16 + 2);
            float p3 = __shfl(pv, quad*16 + 3);
            cacc0 = fmaf(p0, av[0][r], cacc0);
            cacc1 = fmaf(p1, av[1][r], cacc1);
            cacc2 = fmaf(p2, av[2][r], cacc2);
            cacc3 = fmaf(p3, av[3][r], cacc3);
        }
    }
    // cross-quad reduce: cacc_nb -> ctx[nb*16 + l16]; this lane keeps nb=quad
    cacc0 += __shfl_xor(cacc0, 16); cacc0 += __shfl_xor(cacc0, 32);
    cacc1 += __shfl_xor(cacc1, 16); cacc1 += __shfl_xor(cacc1, 32);
    cacc2 += __shfl_xor(cacc2, 16); cacc2 += __shfl_xor(cacc2, 32);
    cacc3 += __shfl_xor(cacc3, 16); cacc3 += __shfl_xor(cacc3, 32);
    float cv = quad == 0 ? cacc0 : quad == 1 ? cacc1 : quad == 2 ? cacc2 : cacc3;
    cv += in_b[128 + c];          // c == quad*16 + l16
    ctx_bf[(size_t)n*64 + c] = (unsigned short)f2bf(cv);
}

// ---------------------------------------------------------------------------
// ffn (MFMA): 80 rows/block x 250 (R9 A/B: 32-row blocks cost +28 MB weight-
// frag reads — keep fat blocks). att = ctx @ Wo^T + bo (A-frags DIRECT from
// global bf16 ctx); y = att + lin2(relu(lin1(att))) -> y_out; BN1 stats.
// ---------------------------------------------------------------------------
__global__ __launch_bounds__(256) void ffn_kernel(
    const float* __restrict__ tw, const float* __restrict__ out_b,
    const float* __restrict__ lin1_b, const float* __restrict__ lin2_b,
    const unsigned short* __restrict__ ctx_bf, float* __restrict__ y_out,
    float* __restrict__ sum1, float* __restrict__ sumsq1)
{
    __shared__ __align__(16) unsigned short sA[80*72];
    __shared__ __align__(16) unsigned short sH[80*264];
    int t = threadIdx.x, base = blockIdx.x * 80;
    int w = t >> 6, lane = t & 63, l16 = lane & 15, quad = lane >> 4;
    const unsigned* WOB = (const unsigned*)(tw + TW_WOB);
    const unsigned* L1B = (const unsigned*)(tw + TW_L1B);
    const unsigned* L2B = (const unsigned*)(tw + TW_L2B);
    bf16x8 wob[2], b1f[2][4], b2f[8];
    #pragma unroll
    for (int ks = 0; ks < 2; ++ks)
        wob[ks] = ldfrag((const unsigned short*)&WOB[((ks*4 + w)*64 + lane)*4]);
    #pragma unroll
    for (int ks = 0; ks < 2; ++ks)
        #pragma unroll
        for (int nb = 0; nb < 4; ++nb)
            b1f[ks][nb] = ldfrag((const unsigned short*)&L1B[((ks*16 + w*4 + nb)*64 + lane)*4]);
    #pragma unroll
    for (int ks = 0; ks < 8; ++ks)
        b2f[ks] = ldfrag((const unsigned short*)&L2B[((ks*4 + w)*64 + lane)*4]);

    // ---- att = ctx @ Wo^T + bo; ctx A-frags straight from global ----
    int c = w*16 + l16;
    float ob = out_b[c];
    f32x4 attacc[5];
    #pragma unroll
    for (int mb = 0; mb < 5; ++mb) {
        const unsigned short* crow = ctx_bf + (size_t)(base + mb*16 + l16)*64;
        bf16x8 a0 = ldfrag(crow + quad*8);
        bf16x8 a1 = ldfrag(crow + 32 + quad*8);
        f32x4 acc = {0.f, 0.f, 0.f, 0.f};
        acc = __builtin_amdgcn_mfma_f32_16x16x32_bf16(a0, wob[0], acc, 0, 0, 0);
        acc = __builtin_amdgcn_mfma_f32_16x16x32_bf16(a1, wob[1], acc, 0, 0, 0);
        #pragma unroll
        for (int reg = 0; reg < 4; ++reg) {
            float av = acc[reg] + ob;
            attacc[mb][reg] = av;
            int row = mb*16 + quad*4 + reg;
            sA[row*72 + c] = (unsigned short)f2bf(av);
        }
    }
    __syncthreads();

    #pragma unroll
    for (int mb = 0; mb < 5; ++mb) {
        bf16x8 a0 = ldfrag(&sA[(mb*16 + l16)*72 + quad*8]);
        bf16x8 a1 = ldfrag(&sA[(mb*16 + l16)*72 + 32 + quad*8]);
        #pragma unroll
        for (int nb = 0; nb < 4; ++nb) {
            f32x4 acc = {0.f, 0.f, 0.f, 0.f};
            acc = __builtin_amdgcn_mfma_f32_16x16x32_bf16(a0, b1f[0][nb], acc, 0, 0, 0);
            acc = __builtin_amdgcn_mfma_f32_16x16x32_bf16(a1, b1f[1][nb], acc, 0, 0, 0);
            int f = w*64 + nb*16 + l16;
            float bias = lin1_b[f];
            #pragma unroll
            for (int reg = 0; reg < 4; ++reg) {
                int row = mb*16 + quad*4 + reg;
                sH[row*264 + f] = (unsigned short)f2bf(fmaxf(acc[reg] + bias, 0.0f));
            }
        }
    }
    __syncthreads();

    float lb2 = lin2_b[c];
    float s = 0.f, ss = 0.f;
    #pragma unroll
    for (int mb = 0; mb < 5; ++mb) {
        f32x4 acc = {0.f, 0.f, 0.f, 0.f};
        #pragma unroll
        for (int ks = 0; ks < 8; ++ks) {
            bf16x8 a = ldfrag(&sH[(mb*16 + l16)*264 + ks*32 + quad*8]);
            acc = __builtin_amdgcn_mfma_f32_16x16x32_bf16(a, b2f[ks], acc, 0, 0, 0);
        }
        #pragma unroll
        for (int reg = 0; reg < 4; ++reg) {
            int r = base + mb*16 + quad*4 + reg;
            float y = attacc[mb][reg] + lb2 + acc[reg];
            y_out[(size_t)r*64 + c] = y;
            s += y; ss = fmaf(y, y, ss);
        }
    }
    s  += __shfl_xor(s, 16);  s  += __shfl_xor(s, 32);
    ss += __shfl_xor(ss, 16); ss += __shfl_xor(ss, 32);
    if (lane < 16) {
        atomicAdd(&sum1[c], s);
        atomicAdd(&sumsq1[c], ss);
    }
}

// ---------------------------------------------------------------------------
// linout (MFMA): 80 rows/block x 250. xn = bn1(y) staged bf16;
// z = xn @ Ol^T + ob -> d_out; BN2 stats.
// ---------------------------------------------------------------------------
__global__ __launch_bounds__(256) void linout_kernel(
    const float* __restrict__ tw, const float* __restrict__ outl_b,
    const float* __restrict__ norm_g, const float* __restrict__ norm_b,
    const float* __restrict__ sum1, const float* __restrict__ sumsq1,
    const float* __restrict__ y, float* __restrict__ z_out,
    float* __restrict__ sum2, float* __restrict__ sumsq2)
{
    __shared__ __align__(16) unsigned short sX[80*72];
    int t = threadIdx.x, base = blockIdx.x * 80;
    int colq = (t*4) & 63;
    const float invN = 1.0f / 20000.0f;
    float4 sm = *(const float4*)&sum1[colq];
    float4 sq = *(const float4*)&sumsq1[colq];
    float4 g  = *(const float4*)&norm_g[colq];
    float4 bb = *(const float4*)&norm_b[colq];
    float mu0 = sm.x*invN, mu1 = sm.y*invN, mu2 = sm.z*invN, mu3 = sm.w*invN;
    float a0 = g.x / sqrtf(fmaf(-mu0, mu0, sq.x*invN) + 1e-5f);
    float a1 = g.y / sqrtf(fmaf(-mu1, mu1, sq.y*invN) + 1e-5f);
    float a2 = g.z / sqrtf(fmaf(-mu2, mu2, sq.z*invN) + 1e-5f);
    float a3 = g.w / sqrtf(fmaf(-mu3, mu3, sq.w*invN) + 1e-5f);
    float b0 = fmaf(-mu0, a0, bb.x), b1 = fmaf(-mu1, a1, bb.y);
    float b2 = fmaf(-mu2, a2, bb.z), b3 = fmaf(-mu3, a3, bb.w);
    #pragma unroll
    for (int i = 0; i < 5; ++i) {
        int e = i*1024 + t*4, r = e >> 6;
        float4 v = *(const float4*)&y[(size_t)(base + r)*64 + colq];
        uint2 p;
        p.x = pk2(fmaf(v.x, a0, b0), fmaf(v.y, a1, b1));
        p.y = pk2(fmaf(v.z, a2, b2), fmaf(v.w, a3, b3));
        *(uint2*)&sX[r*72 + colq] = p;
    }
    int w = t >> 6, lane = t & 63, l16 = lane & 15, quad = lane >> 4;
    const unsigned* OLB = (const unsigned*)(tw + TW_OLB);
    bf16x8 obf[2];
    #pragma unroll
    for (int ks = 0; ks < 2; ++ks)
        obf[ks] = ldfrag((const unsigned short*)&OLB[((ks*4 + w)*64 + lane)*4]);
    __syncthreads();

    int co = w*16 + l16;
    float ob = outl_b[co];
    float s = 0.f, ss = 0.f;
    #pragma unroll
    for (int mb = 0; mb < 5; ++mb) {
        bf16x8 x0 = ldfrag(&sX[(mb*16 + l16)*72 + quad*8]);
        bf16x8 x1 = ldfrag(&sX[(mb*16 + l16)*72 + 32 + quad*8]);
        f32x4 acc = {0.f, 0.f, 0.f, 0.f};
        acc = __builtin_amdgcn_mfma_f32_16x16x32_bf16(x0, obf[0], acc, 0, 0, 0);
        acc = __builtin_amdgcn_mfma_f32_16x16x32_bf16(x1, obf[1], acc, 0, 0, 0);
        #pragma unroll
        for (int reg = 0; reg < 4; ++reg) {
            int r = base + mb*16 + quad*4 + reg;
            float zv = acc[reg] + ob;
            z_out[(size_t)r*64 + co] = zv;
            s += zv; ss = fmaf(zv, zv, ss);
        }
    }
    s  += __shfl_xor(s, 16);  s  += __shfl_xor(s, 32);
    ss += __shfl_xor(ss, 16); ss += __shfl_xor(ss, 32);
    if (lane < 16) {
        atomicAdd(&sum2[co], s);
        atomicAdd(&sumsq2[co], ss);
    }
}

// ---------------------------------------------------------------------------
// out = relu(bn2(z)) in place.
// ---------------------------------------------------------------------------
__global__ void final_kernel(float* __restrict__ z,
    const float* __restrict__ sum2, const float* __restrict__ sumsq2,
    const float* __restrict__ obn_g, const float* __restrict__ obn_b)
{
    int i = blockIdx.x*blockDim.x + threadIdx.x;
    if (i >= N_Q*64/4) return;
    int o4 = (i*4) & 63;
    float4 sm = *(const float4*)&sum2[o4];
    float4 sq = *(const float4*)&sumsq2[o4];
    float4 g  = *(const float4*)&obn_g[o4];
    float4 b  = *(const float4*)&obn_b[o4];
    const float invN = 1.0f / 20000.0f;
    float mux = sm.x*invN, muy = sm.y*invN, muz = sm.z*invN, muw = sm.w*invN;
    float ax = g.x / sqrtf(fmaf(-mux, mux, sq.x*invN) + 1e-5f);
    float ay = g.y / sqrtf(fmaf(-muy, muy, sq.y*invN) + 1e-5f);
    float az = g.z / sqrtf(fmaf(-muz, muz, sq.z*invN) + 1e-5f);
    float aw = g.w / sqrtf(fmaf(-muw, muw, sq.w*invN) + 1e-5f);
    float4 v = ((float4*)z)[i];
    v.x = fmaxf(fmaf(v.x - mux, ax, b.x), 0.0f);
    v.y = fmaxf(fmaf(v.y - muy, ay, b.y), 0.0f);
    v.z = fmaxf(fmaf(v.z - muz, az, b.z), 0.0f);
    v.w = fmaxf(fmaf(v.w - muw, aw, b.w), 0.0f);
    ((float4*)z)[i] = v;
}

extern "C" void kernel_launch(void* const* d_in, const int* in_sizes, int n_in,
                              void* d_out, int out_size, void* d_ws, size_t ws_size,
                              hipStream_t stream)
{
    const float* vfeat  = (const float*)d_in[0];
    const float* vcoord = (const float*)d_in[1];
    const float* qcoord = (const float*)d_in[2];
    const int*   kidx   = (const int*)d_in[3];
    const float* q_w    = (const float*)d_in[4];
    const float* q_b    = (const float*)d_in[5];
    const float* kpos_w = (const float*)d_in[6];
    const float* kpos_b = (const float*)d_in[7];
    const float* in_w   = (const float*)d_in[8];
    const float* in_b   = (const float*)d_in[9];
    const float* out_w  = (const float*)d_in[10];
    const float* out_b  = (const float*)d_in[11];
    const float* lin1_w = (const float*)d_in[12];
    const float* lin1_b = (const float*)d_in[13];
    const float* lin2_w = (const float*)d_in[14];
    const float* lin2_b = (const float*)d_in[15];
    const float* norm_g = (const float*)d_in[16];
    const float* norm_b = (const float*)d_in[17];
    const float* outl_w = (const float*)d_in[18];
    const float* outl_b = (const float*)d_in[19];
    const float* obn_g  = (const float*)d_in[20];
    const float* obn_b  = (const float*)d_in[21];

    float* ws = (float*)d_ws;
    float* tw = ws;
    float* stats = ws + ST_OFF;
    float* sum1 = stats, *sumsq1 = stats + 64, *sum2 = stats + 128, *sumsq2 = stats + 192;
    unsigned short* M_all = (unsigned short*)(ws + M_OFF);
    unsigned short* vfeat_bf = (unsigned short*)(ws + VF_OFF);
    unsigned short* ctx_bf = (unsigned short*)(ws + CTX_OFF);
    float* xd = (float*)d_out;    // y -> z -> out, in place

    prep_m<<<5370, 256, 0, stream>>>(in_w, out_w, lin1_w, lin2_w, outl_w, vfeat,
                                     qcoord, q_w, q_b, in_b, tw, vfeat_bf,
                                     stats, M_all);
    attn_kernel<<<N_Q/4, 256, 0, stream>>>(vfeat_bf, vcoord, qcoord, kidx, kpos_w,
                                           kpos_b, in_b, tw, M_all, ctx_bf);
    ffn_kernel<<<250, 256, 0, stream>>>(tw, out_b, lin1_b, lin2_b, ctx_bf, xd,
                                        sum1, sumsq1);
    linout_kernel<<<250, 256, 0, stream>>>(tw, outl_b, norm_g, norm_b, sum1, sumsq1,
                                           xd, xd, sum2, sumsq2);
    final_kernel<<<1250, 256, 0, stream>>>(xd, sum2, sumsq2, obn_g, obn_b);
}

// Round 12
// 166.234 us; speedup vs baseline: 1.0311x; 1.0311x over previous
//
#include <hip/hip_runtime.h>
#include <math.h>

#define N_Q 20000
#define KK 48
#define CC 64
#define FFD 256

// ws float offsets
#define TW_WOB   0        // 2048 u32: out_w B-frags [ks2][nb4][lane64][4] (ffn att GEMM)
#define TW_WVT   4096     // 2048 u32: Wv B-frags [ks2][nb4][lane64][4]   (attn V-GEMM)
#define TW_L1B   8192     // 8192 u32: lin1 B-frags  [ks2][nb16][lane64][4]
#define TW_L2B   16384    // 8192 u32: lin2 B-frags  [ks8][nb4][lane64][4]
#define TW_OLB   24576    // 2048 u32: outl B-frags  [ks2][nb4][lane64][4]
#define ST_OFF   32768    // 256 f32: sum1,sumsq1,sum2,sumsq2
#define M_OFF    33024    // bf16 M_all[n][h*64+c], 20000*256 ushorts
#define VF_OFF   2593024  // bf16 vfeat table, 80000*64 ushorts (10.24 MB)
#define CTX_OFF  5153024  // bf16 ctx[n][c], 20000*64 ushorts (2.56 MB)

typedef short bf16x8 __attribute__((ext_vector_type(8)));
typedef float f32x4  __attribute__((ext_vector_type(4)));

// v_cvt_pk_bf16_f32: 1 VALU op, RNE.
__device__ __forceinline__ unsigned pk2(float a, float b) {
    unsigned r;
    asm("v_cvt_pk_bf16_f32 %0, %1, %2" : "=v"(r) : "v"(a), "v"(b));
    return r;
}
__device__ __forceinline__ unsigned f2bf(float a) {
    unsigned r;
    asm("v_cvt_pk_bf16_f32 %0, %1, 0" : "=v"(r) : "v"(a));
    return r & 0xffffu;
}
__device__ __forceinline__ float bflo(unsigned u) { return __uint_as_float(u << 16); }
__device__ __forceinline__ float bfhi(unsigned u) { return __uint_as_float(u & 0xffff0000u); }
__device__ __forceinline__ bf16x8 ldfrag(const unsigned short* p) {
    return *(const bf16x8*)p;
}
union U84 { unsigned u[4]; bf16x8 v; };

// ---------------------------------------------------------------------------
// prep_m: fused. Blocks 0..249: m-work (self-packed QB/KB frags from in_w —
// bit-identical pk2). Blocks 250..5369: prep-work (vfeat bf16 table, weight
// B-frag packs, stats zero). Single launch removes the prep->m dependency.
// ---------------------------------------------------------------------------
__global__ __launch_bounds__(256) void prep_m(
    const float* __restrict__ in_w, const float* __restrict__ out_w,
    const float* __restrict__ lin1_w, const float* __restrict__ lin2_w,
    const float* __restrict__ outl_w, const float* __restrict__ vfeat,
    const float* __restrict__ qcoord, const float* __restrict__ q_w,
    const float* __restrict__ q_b, const float* __restrict__ in_b,
    float* __restrict__ tw, unsigned short* __restrict__ vfeat_bf,
    float* __restrict__ stats, unsigned short* __restrict__ M_all)
{
    __shared__ __align__(16) unsigned short sQF[80*72];
    __shared__ __align__(16) unsigned short sQ[80*72];

    if (blockIdx.x >= 250) {
        // ---------------- prep path ----------------
        int t = (blockIdx.x - 250) * 256 + threadIdx.x;
        unsigned* twu = (unsigned*)tw;
        if (t < 1280000) {                          // vfeat -> bf16 (4 elems/thread)
            float4 v = ((const float4*)vfeat)[t];
            uint2 p; p.x = pk2(v.x, v.y); p.y = pk2(v.z, v.w);
            ((uint2*)vfeat_bf)[t] = p;
        }
        if (t < 256) stats[t] = 0.0f;
        if (t < 4096) {
            if (t < 2048) {                        // WOB: att = ctx @ out_w^T (ffn)
                int p = t;
                int j2 = p & 3, lane = (p >> 2) & 63, nb = (p >> 8) & 3, ks = p >> 10;
                int nn = nb*16 + (lane & 15), k = ks*32 + (lane >> 4)*8 + 2*j2;
                twu[TW_WOB + p] = pk2(out_w[nn*64 + k], out_w[nn*64 + k + 1]);
            }
        } else if (t < 8192) {
            if (t < 6144) {                        // VB: Wv B-frags (attn V-GEMM)
                int p = t - 4096;
                int j2 = p & 3, lane = (p >> 2) & 63, nb = (p >> 8) & 3, ks = p >> 10;
                int nn = nb*16 + (lane & 15), k = ks*32 + (lane >> 4)*8 + 2*j2;
                twu[TW_WVT + p] = pk2(in_w[(128 + nn)*64 + k], in_w[(128 + nn)*64 + k + 1]);
            }
        } else if (t < 16384) {                    // L1B: H = att @ lin1_w^T
            int p = t - 8192;
            int j2 = p & 3, lane = (p >> 2) & 63, nb = (p >> 8) & 15, ks = p >> 12;
            int n = nb*16 + (lane & 15), k = ks*32 + (lane >> 4)*8 + 2*j2;
            twu[TW_L1B + p] = pk2(lin1_w[n*64 + k], lin1_w[n*64 + k + 1]);
        } else if (t < 24576) {                    // L2B: Y = H @ lin2_w^T
            int p = t - 16384;
            int j2 = p & 3, lane = (p >> 2) & 63, nb = (p >> 8) & 3, ks = p >> 10;
            int n = nb*16 + (lane & 15), k = ks*32 + (lane >> 4)*8 + 2*j2;
            twu[TW_L2B + p] = pk2(lin2_w[n*256 + k], lin2_w[n*256 + k + 1]);
        } else if (t < 26624) {                    // OLB: z = xn @ outl_w^T
            int p = t - 24576;
            int j2 = p & 3, lane = (p >> 2) & 63, nb = (p >> 8) & 3, ks = p >> 10;
            int n = nb*16 + (lane & 15), k = ks*32 + (lane >> 4)*8 + 2*j2;
            twu[TW_OLB + p] = pk2(outl_w[n*64 + k], outl_w[n*64 + k + 1]);
        }
        return;
    }

    // ---------------- m path (blocks 0..249) ----------------
    int t = threadIdx.x, base = blockIdx.x * 80;
    int colq = (t*4) & 63;
    float qwv[12];
    #pragma unroll
    for (int j = 0; j < 12; ++j) qwv[j] = q_w[colq*3 + j];
    float4 qb4 = *(const float4*)&q_b[colq];
    #pragma unroll
    for (int i = 0; i < 5; ++i) {
        int e = i*1024 + t*4, r = e >> 6, n = base + r;
        float c0 = qcoord[n*3], c1 = qcoord[n*3+1], c2 = qcoord[n*3+2];
        float f0 = fmaxf(fmaf(qwv[2],  c2, fmaf(qwv[1],  c1, fmaf(qwv[0], c0, qb4.x))), 0.f);
        float f1 = fmaxf(fmaf(qwv[5],  c2, fmaf(qwv[4],  c1, fmaf(qwv[3], c0, qb4.y))), 0.f);
        float f2 = fmaxf(fmaf(qwv[8],  c2, fmaf(qwv[7],  c1, fmaf(qwv[6], c0, qb4.z))), 0.f);
        float f3 = fmaxf(fmaf(qwv[11], c2, fmaf(qwv[10], c1, fmaf(qwv[9], c0, qb4.w))), 0.f);
        uint2 p; p.x = pk2(f0, f1); p.y = pk2(f2, f3);
        *(uint2*)&sQF[r*72 + colq] = p;
    }
    int w = t >> 6, lane = t & 63, l16 = lane & 15, quad = lane >> 4;
    // self-pack qbf (Wq B-frags): contiguous 8 f32 of in_w row (w*16+l16)
    bf16x8 qbf[2], kbf[4];
    {
        const float* qrow = in_w + (w*16 + l16)*64;
        #pragma unroll
        for (int ks = 0; ks < 2; ++ks) {
            float4 aa = *(const float4*)&qrow[ks*32 + quad*8];
            float4 bb = *(const float4*)&qrow[ks*32 + quad*8 + 4];
            U84 u;
            u.u[0] = pk2(aa.x, aa.y); u.u[1] = pk2(aa.z, aa.w);
            u.u[2] = pk2(bb.x, bb.y); u.u[3] = pk2(bb.z, bb.w);
            qbf[ks] = u.v;
        }
        // self-pack kbf (Wk B-frags, head w, K=16 zero-pad for quad>=2)
        #pragma unroll
        for (int nb = 0; nb < 4; ++nb) {
            U84 u;
            if (quad < 2) {
                int jj = nb*16 + l16;
                #pragma unroll
                for (int j2 = 0; j2 < 4; ++j2) {
                    int k = quad*8 + 2*j2;
                    u.u[j2] = pk2(in_w[(64 + w*16 + k)*64 + jj],
                                  in_w[(64 + w*16 + k + 1)*64 + jj]);
                }
            } else {
                u.u[0] = u.u[1] = u.u[2] = u.u[3] = 0;
            }
            kbf[nb] = u.v;
        }
    }
    __syncthreads();

    int cq = w*16 + l16;
    float bq = in_b[cq];
    #pragma unroll
    for (int mb = 0; mb < 5; ++mb) {
        bf16x8 a0 = ldfrag(&sQF[(mb*16 + l16)*72 + quad*8]);
        bf16x8 a1 = ldfrag(&sQF[(mb*16 + l16)*72 + 32 + quad*8]);
        f32x4 acc = {0.f, 0.f, 0.f, 0.f};
        acc = __builtin_amdgcn_mfma_f32_16x16x32_bf16(a0, qbf[0], acc, 0, 0, 0);
        acc = __builtin_amdgcn_mfma_f32_16x16x32_bf16(a1, qbf[1], acc, 0, 0, 0);
        #pragma unroll
        for (int reg = 0; reg < 4; ++reg) {
            int row = mb*16 + quad*4 + reg;
            sQ[row*72 + cq] = (unsigned short)f2bf((acc[reg] + bq) * 0.25f);
        }
    }
    // per-head M GEMM: head h = w reads exactly the cols it wrote (in-order)
    #pragma unroll
    for (int mb = 0; mb < 5; ++mb) {
        bf16x8 a = {0,0,0,0,0,0,0,0};
        if (quad < 2) a = ldfrag(&sQ[(mb*16 + l16)*72 + w*16 + quad*8]);
        f32x4 acc[4];
        #pragma unroll
        for (int nb = 0; nb < 4; ++nb) {
            f32x4 z = {0.f, 0.f, 0.f, 0.f};
            acc[nb] = __builtin_amdgcn_mfma_f32_16x16x32_bf16(a, kbf[nb], z, 0, 0, 0);
        }
        #pragma unroll
        for (int nb = 0; nb < 4; ++nb)
            #pragma unroll
            for (int reg = 0; reg < 4; ++reg) {
                int r = base + mb*16 + quad*4 + reg, j = nb*16 + l16;
                M_all[(size_t)r*256 + w*64 + j] = (unsigned short)f2bf(acc[nb][reg]);
            }
    }
}

// ---------------------------------------------------------------------------
// attn: 4 queries/block (256 thr, 4 independent waves, disjoint LDS quarters,
// barrier-free). 16B bf16 gathers -> bf16 KF in LDS [key][c^swz]: tight
// 64-col pitch + T2 XOR swizzle (ushort idx ^= (row&7)<<3, 16B granule) —
// 24 KB/block, 0 bank conflicts (verified R7). launch_bounds(256,4): do NOT
// over-constrain VGPRs — (256,6) clamped to 40 VGPR and spilled ~250 MB of
// scratch traffic (R7 post-mortem). R9 A/B: keep 4q blocks. R11 A/B:
// scalar fmaf beats inline-asm v_pk_fma_f32 here (pairing moves + opaque
// scheduling cost more than the packed issue saves).
// ---------------------------------------------------------------------------
__global__ __launch_bounds__(256, 4) void attn_kernel(
    const unsigned short* __restrict__ vfeat_bf, const float* __restrict__ vcoord,
    const float* __restrict__ qcoord, const int* __restrict__ kidx,
    const float* __restrict__ kpos_w, const float* __restrict__ kpos_b,
    const float* __restrict__ in_b,
    const float* __restrict__ tw, const unsigned short* __restrict__ M_all,
    unsigned short* __restrict__ ctx_bf)
{
    __shared__ __align__(16) unsigned short skf2[4][KK*64];  // 4 x 6144 B
    int wv = threadIdx.x >> 6, c = threadIdx.x & 63;
    int n = blockIdx.x * 4 + wv;
    unsigned short* skf = skf2[wv];
    int l16 = c & 15, quad = c >> 4;

    // ---- early loads: M score B-frags (dup head l16&3) + Wv B-frags ----
    const unsigned short* Mrow = M_all + (size_t)n*256 + (l16 & 3)*64 + quad*8;
    bf16x8 mf0 = ldfrag(Mrow);          // k-dim c = quad*8 + j      (ks=0)
    bf16x8 mf1 = ldfrag(Mrow + 32);     // k-dim c = 32 + quad*8 + j (ks=1)
    const unsigned* VBu = (const unsigned*)(tw + TW_WVT);
    bf16x8 wvf[2][4];
    #pragma unroll
    for (int ks = 0; ks < 2; ++ks)
        #pragma unroll
        for (int nb = 0; nb < 4; ++nb)
            wvf[ks][nb] = ldfrag((const unsigned short*)&VBu[((ks*4 + nb)*64 + c)*4]);

    float qc0 = qcoord[n*3+0], qc1 = qcoord[n*3+1], qc2 = qcoord[n*3+2];

    // lanes 0..47: key index + relative coords
    int kread = c < 48 ? c : 47;
    int idxv = kidx[(size_t)n*KK + kread];
    int sfe = idxv < 0 ? 0 : idxv;
    float rl0 = vcoord[sfe*3+0] - qc0;
    float rl1 = vcoord[sfe*3+1] - qc1;
    float rl2 = vcoord[sfe*3+2] - qc2;

    // kpos params for this lane's 8 channels (j = (c&7)*8 + 0..7)
    int o8 = c >> 3, jb8 = (c & 7) * 8;
    float w8[24], b8[8];
    #pragma unroll
    for (int q = 0; q < 6; ++q)
        *(float4*)&w8[q*4] = *(const float4*)(kpos_w + jb8*3 + q*4);
    *(float4*)&b8[0] = *(const float4*)(kpos_b + jb8);
    *(float4*)&b8[4] = *(const float4*)(kpos_b + jb8 + 4);

    // ---- issue all 6 gather loads (16B/lane: 8 bf16 channels) ----
    uint4 fv[6];
    #pragma unroll
    for (int i = 0; i < 6; ++i) {
        int row = 8*i + o8;
        int si = __shfl(idxv, row);
        si = si < 0 ? 0 : si;
        fv[i] = *(const uint4*)(vfeat_bf + (size_t)si*64 + jb8);
    }
    // ---- consume: unpack, add positional encoding, repack to swizzled LDS ----
    #pragma unroll
    for (int i = 0; i < 6; ++i) {
        int row = 8*i + o8;
        float rr0 = __shfl(rl0, row), rr1 = __shfl(rl1, row), rr2 = __shfl(rl2, row);
        unsigned uu[4] = {fv[i].x, fv[i].y, fv[i].z, fv[i].w};
        unsigned pp[4];
        #pragma unroll
        for (int q2 = 0; q2 < 4; ++q2) {
            int k0 = 2*q2, k1 = 2*q2 + 1;
            float gl = bflo(uu[q2]), gh = bfhi(uu[q2]);
            gl += fmaxf(fmaf(w8[3*k0+2], rr2, fmaf(w8[3*k0+1], rr1, fmaf(w8[3*k0], rr0, b8[k0]))), 0.f);
            gh += fmaxf(fmaf(w8[3*k1+2], rr2, fmaf(w8[3*k1+1], rr1, fmaf(w8[3*k1], rr0, b8[k1]))), 0.f);
            pp[q2] = pk2(gl, gh);
        }
        uint4 st; st.x = pp[0]; st.y = pp[1]; st.z = pp[2]; st.w = pp[3];
        *(uint4*)&skf[row*64 + (jb8 ^ ((row & 7) << 3))] = st;
    }

    // ---- scores: S = KF @ M via MFMA; D[row=key-in-tile, col=head] ----
    unsigned long long vm = __ballot(c < 48 && idxv >= 0);
    bf16x8 a0s[3], a1s[3];
    float S[3][4];
    #pragma unroll
    for (int mb = 0; mb < 3; ++mb) {
        int r0 = mb*16 + l16, sw = (l16 & 7) << 3;
        a0s[mb] = ldfrag(&skf[r0*64 + ((quad*8) ^ sw)]);
        a1s[mb] = ldfrag(&skf[r0*64 + ((32 + quad*8) ^ sw)]);
        f32x4 acc = {0.f, 0.f, 0.f, 0.f};
        acc = __builtin_amdgcn_mfma_f32_16x16x32_bf16(a0s[mb], mf0, acc, 0, 0, 0);
        acc = __builtin_amdgcn_mfma_f32_16x16x32_bf16(a1s[mb], mf1, acc, 0, 0, 0);
        #pragma unroll
        for (int r = 0; r < 4; ++r) {
            int kk = mb*16 + quad*4 + r;
            S[mb][r] = ((vm >> kk) & 1ull) ? acc[r] : -1e30f;
        }
    }

    // ---- softmax over the 48 keys of head (l16&3); reduce across quads ----
    float mx = S[0][0];
    #pragma unroll
    for (int mb = 0; mb < 3; ++mb)
        #pragma unroll
        for (int r = 0; r < 4; ++r) mx = fmaxf(mx, S[mb][r]);
    mx = fmaxf(mx, __shfl_xor(mx, 16));
    mx = fmaxf(mx, __shfl_xor(mx, 32));
    float p[3][4], es = 0.f;
    #pragma unroll
    for (int mb = 0; mb < 3; ++mb)
        #pragma unroll
        for (int r = 0; r < 4; ++r) { p[mb][r] = __expf(S[mb][r] - mx); es += p[mb][r]; }
    es += __shfl_xor(es, 16);
    es += __shfl_xor(es, 32);
    float rinv = 1.0f / es;
    #pragma unroll
    for (int mb = 0; mb < 3; ++mb)
        #pragma unroll
        for (int r = 0; r < 4; ++r) p[mb][r] *= rinv;

    // ---- V = KF @ Wv^T (MFMA, reuses a-frags); ctx = P @ V (f32) ----
    float cacc0 = 0.f, cacc1 = 0.f, cacc2 = 0.f, cacc3 = 0.f;
    #pragma unroll
    for (int mb = 0; mb < 3; ++mb) {
        f32x4 av[4];
        #pragma unroll
        for (int nb = 0; nb < 4; ++nb) {
            f32x4 z = {0.f, 0.f, 0.f, 0.f};
            z = __builtin_amdgcn_mfma_f32_16x16x32_bf16(a0s[mb], wvf[0][nb], z, 0, 0, 0);
            av[nb] = __builtin_amdgcn_mfma_f32_16x16x32_bf16(a1s[mb], wvf[1][nb], z, 0, 0, 0);
        }
        #pragma unroll
        for (int r = 0; r < 4; ++r) {
            float pv = p[mb][r];
            float p0 = __shfl(pv, quad*16 + 0);
            float p1 = __shfl(pv, quad*16 + 1);
            float p2 = __shfl(pv, quad*16 + 2);
            float p3 = __shfl(pv, quad*16 + 3);
            cacc0 = fmaf(p0, av[0][r], cacc0);
            cacc1 = fmaf(p1, av[1][r], cacc1);
            cacc2 = fmaf(p2, av[2][r], cacc2);
            cacc3 = fmaf(p3, av[3][r], cacc3);
        }
    }
    // cross-quad reduce: cacc_nb -> ctx[nb*16 + l16]; this lane keeps nb=quad
    cacc0 += __shfl_xor(cacc0, 16); cacc0 += __shfl_xor(cacc0, 32);
    cacc1 += __shfl_xor(cacc1, 16); cacc1 += __shfl_xor(cacc1, 32);
    cacc2 += __shfl_xor(cacc2, 16); cacc2 += __shfl_xor(cacc2, 32);
    cacc3 += __shfl_xor(cacc3, 16); cacc3 += __shfl_xor(cacc3, 32);
    float cv = quad == 0 ? cacc0 : quad == 1 ? cacc1 : quad == 2 ? cacc2 : cacc3;
    cv += in_b[128 + c];          // c == quad*16 + l16
    ctx_bf[(size_t)n*64 + c] = (unsigned short)f2bf(cv);
}

// ---------------------------------------------------------------------------
// ffn (MFMA): 80 rows/block x 250 (R9 A/B: 32-row blocks cost +28 MB weight-
// frag reads — keep fat blocks). att = ctx @ Wo^T + bo (A-frags DIRECT from
// global bf16 ctx); y = att + lin2(relu(lin1(att))) -> y_out; BN1 stats.
// ---------------------------------------------------------------------------
__global__ __launch_bounds__(256) void ffn_kernel(
    const float* __restrict__ tw, const float* __restrict__ out_b,
    const float* __restrict__ lin1_b, const float* __restrict__ lin2_b,
    const unsigned short* __restrict__ ctx_bf, float* __restrict__ y_out,
    float* __restrict__ sum1, float* __restrict__ sumsq1)
{
    __shared__ __align__(16) unsigned short sA[80*72];
    __shared__ __align__(16) unsigned short sH[80*264];
    int t = threadIdx.x, base = blockIdx.x * 80;
    int w = t >> 6, lane = t & 63, l16 = lane & 15, quad = lane >> 4;
    const unsigned* WOB = (const unsigned*)(tw + TW_WOB);
    const unsigned* L1B = (const unsigned*)(tw + TW_L1B);
    const unsigned* L2B = (const unsigned*)(tw + TW_L2B);
    bf16x8 wob[2], b1f[2][4], b2f[8];
    #pragma unroll
    for (int ks = 0; ks < 2; ++ks)
        wob[ks] = ldfrag((const unsigned short*)&WOB[((ks*4 + w)*64 + lane)*4]);
    #pragma unroll
    for (int ks = 0; ks < 2; ++ks)
        #pragma unroll
        for (int nb = 0; nb < 4; ++nb)
            b1f[ks][nb] = ldfrag((const unsigned short*)&L1B[((ks*16 + w*4 + nb)*64 + lane)*4]);
    #pragma unroll
    for (int ks = 0; ks < 8; ++ks)
        b2f[ks] = ldfrag((const unsigned short*)&L2B[((ks*4 + w)*64 + lane)*4]);

    // ---- att = ctx @ Wo^T + bo; ctx A-frags straight from global ----
    int c = w*16 + l16;
    float ob = out_b[c];
    f32x4 attacc[5];
    #pragma unroll
    for (int mb = 0; mb < 5; ++mb) {
        const unsigned short* crow = ctx_bf + (size_t)(base + mb*16 + l16)*64;
        bf16x8 a0 = ldfrag(crow + quad*8);
        bf16x8 a1 = ldfrag(crow + 32 + quad*8);
        f32x4 acc = {0.f, 0.f, 0.f, 0.f};
        acc = __builtin_amdgcn_mfma_f32_16x16x32_bf16(a0, wob[0], acc, 0, 0, 0);
        acc = __builtin_amdgcn_mfma_f32_16x16x32_bf16(a1, wob[1], acc, 0, 0, 0);
        #pragma unroll
        for (int reg = 0; reg < 4; ++reg) {
            float av = acc[reg] + ob;
            attacc[mb][reg] = av;
            int row = mb*16 + quad*4 + reg;
            sA[row*72 + c] = (unsigned short)f2bf(av);
        }
    }
    __syncthreads();

    #pragma unroll
    for (int mb = 0; mb < 5; ++mb) {
        bf16x8 a0 = ldfrag(&sA[(mb*16 + l16)*72 + quad*8]);
        bf16x8 a1 = ldfrag(&sA[(mb*16 + l16)*72 + 32 + quad*8]);
        #pragma unroll
        for (int nb = 0; nb < 4; ++nb) {
            f32x4 acc = {0.f, 0.f, 0.f, 0.f};
            acc = __builtin_amdgcn_mfma_f32_16x16x32_bf16(a0, b1f[0][nb], acc, 0, 0, 0);
            acc = __builtin_amdgcn_mfma_f32_16x16x32_bf16(a1, b1f[1][nb], acc, 0, 0, 0);
            int f = w*64 + nb*16 + l16;
            float bias = lin1_b[f];
            #pragma unroll
            for (int reg = 0; reg < 4; ++reg) {
                int row = mb*16 + quad*4 + reg;
                sH[row*264 + f] = (unsigned short)f2bf(fmaxf(acc[reg] + bias, 0.0f));
            }
        }
    }
    __syncthreads();

    float lb2 = lin2_b[c];
    float s = 0.f, ss = 0.f;
    #pragma unroll
    for (int mb = 0; mb < 5; ++mb) {
        f32x4 acc = {0.f, 0.f, 0.f, 0.f};
        #pragma unroll
        for (int ks = 0; ks < 8; ++ks) {
            bf16x8 a = ldfrag(&sH[(mb*16 + l16)*264 + ks*32 + quad*8]);
            acc = __builtin_amdgcn_mfma_f32_16x16x32_bf16(a, b2f[ks], acc, 0, 0, 0);
        }
        #pragma unroll
        for (int reg = 0; reg < 4; ++reg) {
            int r = base + mb*16 + quad*4 + reg;
            float y = attacc[mb][reg] + lb2 + acc[reg];
            y_out[(size_t)r*64 + c] = y;
            s += y; ss = fmaf(y, y, ss);
        }
    }
    s  += __shfl_xor(s, 16);  s  += __shfl_xor(s, 32);
    ss += __shfl_xor(ss, 16); ss += __shfl_xor(ss, 32);
    if (lane < 16) {
        atomicAdd(&sum1[c], s);
        atomicAdd(&sumsq1[c], ss);
    }
}

// ---------------------------------------------------------------------------
// linout (MFMA): 80 rows/block x 250. xn = bn1(y) staged bf16;
// z = xn @ Ol^T + ob -> d_out; BN2 stats.
// ---------------------------------------------------------------------------
__global__ __launch_bounds__(256) void linout_kernel(
    const float* __restrict__ tw, const float* __restrict__ outl_b,
    const float* __restrict__ norm_g, const float* __restrict__ norm_b,
    const float* __restrict__ sum1, const float* __restrict__ sumsq1,
    const float* __restrict__ y, float* __restrict__ z_out,
    float* __restrict__ sum2, float* __restrict__ sumsq2)
{
    __shared__ __align__(16) unsigned short sX[80*72];
    int t = threadIdx.x, base = blockIdx.x * 80;
    int colq = (t*4) & 63;
    const float invN = 1.0f / 20000.0f;
    float4 sm = *(const float4*)&sum1[colq];
    float4 sq = *(const float4*)&sumsq1[colq];
    float4 g  = *(const float4*)&norm_g[colq];
    float4 bb = *(const float4*)&norm_b[colq];
    float mu0 = sm.x*invN, mu1 = sm.y*invN, mu2 = sm.z*invN, mu3 = sm.w*invN;
    float a0 = g.x / sqrtf(fmaf(-mu0, mu0, sq.x*invN) + 1e-5f);
    float a1 = g.y / sqrtf(fmaf(-mu1, mu1, sq.y*invN) + 1e-5f);
    float a2 = g.z / sqrtf(fmaf(-mu2, mu2, sq.z*invN) + 1e-5f);
    float a3 = g.w / sqrtf(fmaf(-mu3, mu3, sq.w*invN) + 1e-5f);
    float b0 = fmaf(-mu0, a0, bb.x), b1 = fmaf(-mu1, a1, bb.y);
    float b2 = fmaf(-mu2, a2, bb.z), b3 = fmaf(-mu3, a3, bb.w);
    #pragma unroll
    for (int i = 0; i < 5; ++i) {
        int e = i*1024 + t*4, r = e >> 6;
        float4 v = *(const float4*)&y[(size_t)(base + r)*64 + colq];
        uint2 p;
        p.x = pk2(fmaf(v.x, a0, b0), fmaf(v.y, a1, b1));
        p.y = pk2(fmaf(v.z, a2, b2), fmaf(v.w, a3, b3));
        *(uint2*)&sX[r*72 + colq] = p;
    }
    int w = t >> 6, lane = t & 63, l16 = lane & 15, quad = lane >> 4;
    const unsigned* OLB = (const unsigned*)(tw + TW_OLB);
    bf16x8 obf[2];
    #pragma unroll
    for (int ks = 0; ks < 2; ++ks)
        obf[ks] = ldfrag((const unsigned short*)&OLB[((ks*4 + w)*64 + lane)*4]);
    __syncthreads();

    int co = w*16 + l16;
    float ob = outl_b[co];
    float s = 0.f, ss = 0.f;
    #pragma unroll
    for (int mb = 0; mb < 5; ++mb) {
        bf16x8 x0 = ldfrag(&sX[(mb*16 + l16)*72 + quad*8]);
        bf16x8 x1 = ldfrag(&sX[(mb*16 + l16)*72 + 32 + quad*8]);
        f32x4 acc = {0.f, 0.f, 0.f, 0.f};
        acc = __builtin_amdgcn_mfma_f32_16x16x32_bf16(x0, obf[0], acc, 0, 0, 0);
        acc = __builtin_amdgcn_mfma_f32_16x16x32_bf16(x1, obf[1], acc, 0, 0, 0);
        #pragma unroll
        for (int reg = 0; reg < 4; ++reg) {
            int r = base + mb*16 + quad*4 + reg;
            float zv = acc[reg] + ob;
            z_out[(size_t)r*64 + co] = zv;
            s += zv; ss = fmaf(zv, zv, ss);
        }
    }
    s  += __shfl_xor(s, 16);  s  += __shfl_xor(s, 32);
    ss += __shfl_xor(ss, 16); ss += __shfl_xor(ss, 32);
    if (lane < 16) {
        atomicAdd(&sum2[co], s);
        atomicAdd(&sumsq2[co], ss);
    }
}

// ---------------------------------------------------------------------------
// out = relu(bn2(z)) in place.
// ---------------------------------------------------------------------------
__global__ void final_kernel(float* __restrict__ z,
    const float* __restrict__ sum2, const float* __restrict__ sumsq2,
    const float* __restrict__ obn_g, const float* __restrict__ obn_b)
{
    int i = blockIdx.x*blockDim.x + threadIdx.x;
    if (i >= N_Q*64/4) return;
    int o4 = (i*4) & 63;
    float4 sm = *(const float4*)&sum2[o4];
    float4 sq = *(const float4*)&sumsq2[o4];
    float4 g  = *(const float4*)&obn_g[o4];
    float4 b  = *(const float4*)&obn_b[o4];
    const float invN = 1.0f / 20000.0f;
    float mux = sm.x*invN, muy = sm.y*invN, muz = sm.z*invN, muw = sm.w*invN;
    float ax = g.x / sqrtf(fmaf(-mux, mux, sq.x*invN) + 1e-5f);
    float ay = g.y / sqrtf(fmaf(-muy, muy, sq.y*invN) + 1e-5f);
    float az = g.z / sqrtf(fmaf(-muz, muz, sq.z*invN) + 1e-5f);
    float aw = g.w / sqrtf(fmaf(-muw, muw, sq.w*invN) + 1e-5f);
    float4 v = ((float4*)z)[i];
    v.x = fmaxf(fmaf(v.x - mux, ax, b.x), 0.0f);
    v.y = fmaxf(fmaf(v.y - muy, ay, b.y), 0.0f);
    v.z = fmaxf(fmaf(v.z - muz, az, b.z), 0.0f);
    v.w = fmaxf(fmaf(v.w - muw, aw, b.w), 0.0f);
    ((float4*)z)[i] = v;
}

extern "C" void kernel_launch(void* const* d_in, const int* in_sizes, int n_in,
                              void* d_out, int out_size, void* d_ws, size_t ws_size,
                              hipStream_t stream)
{
    const float* vfeat  = (const float*)d_in[0];
    const float* vcoord = (const float*)d_in[1];
    const float* qcoord = (const float*)d_in[2];
    const int*   kidx   = (const int*)d_in[3];
    const float* q_w    = (const float*)d_in[4];
    const float* q_b    = (const float*)d_in[5];
    const float* kpos_w = (const float*)d_in[6];
    const float* kpos_b = (const float*)d_in[7];
    const float* in_w   = (const float*)d_in[8];
    const float* in_b   = (const float*)d_in[9];
    const float* out_w  = (const float*)d_in[10];
    const float* out_b  = (const float*)d_in[11];
    const float* lin1_w = (const float*)d_in[12];
    const float* lin1_b = (const float*)d_in[13];
    const float* lin2_w = (const float*)d_in[14];
    const float* lin2_b = (const float*)d_in[15];
    const float* norm_g = (const float*)d_in[16];
    const float* norm_b = (const float*)d_in[17];
    const float* outl_w = (const float*)d_in[18];
    const float* outl_b = (const float*)d_in[19];
    const float* obn_g  = (const float*)d_in[20];
    const float* obn_b  = (const float*)d_in[21];

    float* ws = (float*)d_ws;
    float* tw = ws;
    float* stats = ws + ST_OFF;
    float* sum1 = stats, *sumsq1 = stats + 64, *sum2 = stats + 128, *sumsq2 = stats + 192;
    unsigned short* M_all = (unsigned short*)(ws + M_OFF);
    unsigned short* vfeat_bf = (unsigned short*)(ws + VF_OFF);
    unsigned short* ctx_bf = (unsigned short*)(ws + CTX_OFF);
    float* xd = (float*)d_out;    // y -> z -> out, in place

    prep_m<<<5370, 256, 0, stream>>>(in_w, out_w, lin1_w, lin2_w, outl_w, vfeat,
                                     qcoord, q_w, q_b, in_b, tw, vfeat_bf,
                                     stats, M_all);
    attn_kernel<<<N_Q/4, 256, 0, stream>>>(vfeat_bf, vcoord, qcoord, kidx, kpos_w,
                                           kpos_b, in_b, tw, M_all, ctx_bf);
    ffn_kernel<<<250, 256, 0, stream>>>(tw, out_b, lin1_b, lin2_b, ctx_bf, xd,
                                        sum1, sumsq1);
    linout_kernel<<<250, 256, 0, stream>>>(tw, outl_b, norm_g, norm_b, sum1, sumsq1,
                                           xd, xd, sum2, sumsq2);
    final_kernel<<<1250, 256, 0, stream>>>(xd, sum2, sumsq2, obn_g, obn_b);
}